// Round 4
// baseline (2374.300 us; speedup 1.0000x reference)
//
#include <hip/hip_runtime.h>
#include <cstdint>
#include <cstddef>

typedef unsigned int u32;
typedef unsigned short u16;
typedef __attribute__((ext_vector_type(8))) short s16x8;
typedef __attribute__((ext_vector_type(4))) float f32x4;

#define MFMA(a,b,c) __builtin_amdgcn_mfma_f32_16x16x32_bf16((a),(b),(c),0,0,0)

__device__ __forceinline__ u32 f2bf(float f){ union{float f;u32 u;}v; v.f=f; return (v.u + 0x7FFFu + ((v.u>>16)&1u))>>16; }
__device__ __forceinline__ float bflo(u32 p){ union{u32 u;float f;}v; v.u=p<<16; return v.f; }
__device__ __forceinline__ float bfhi(u32 p){ union{u32 u;float f;}v; v.u=p&0xFFFF0000u; return v.f; }
__device__ __forceinline__ float sigm(float x){ return __builtin_amdgcn_rcpf(1.0f + __builtin_amdgcn_exp2f(-1.4426950408889634f*x)); }
__device__ __forceinline__ float tanh_(float x){ return 1.0f - 2.0f*__builtin_amdgcn_rcpf(1.0f + __builtin_amdgcn_exp2f(2.8853900817779268f*x)); }

// node_init (fp32) -> shadow (bf16) for non-leaf own rows [0, 37449). total8 = elems/8.
__global__ void conv_nodes(const float* __restrict__ src, u16* __restrict__ dst, long total8) {
    long i = (long)blockIdx.x*256 + threadIdx.x;
    if (i < total8) {
        const float* s = src + i*8;
        float4 f0 = *(const float4*)s;
        float4 f1 = *(const float4*)(s+4);
        uint4 pk;
        pk.x = f2bf(f0.x) | (f2bf(f0.y)<<16);
        pk.y = f2bf(f0.z) | (f2bf(f0.w)<<16);
        pk.z = f2bf(f1.x) | (f2bf(f1.y)<<16);
        pk.w = f2bf(f1.z) | (f2bf(f1.w)<<16);
        *(uint4*)(dst + i*8) = pk;
    }
}

// Packed weight layout (gather-free B-fragments):
// LSTM mats: block b = ((wv*4+u)*4+g)*8+kc, flat = b*512 + lane*8 + j
//   source row (torch order) = g*256 + wv*64 + u*16 + lrow, col = kc*32 + quad*8 + j
// Wenc: block = ((wv*4+u2)*2+half)*8+kc, flat = blk*512 + lane*8 + j
//   source row ce = wv*64+u2*16+lrow, col = half*256 + kc*32 + quad*8 + j
__global__ void prep_weights(const float* Wih_l, const float* Whh_l, const float* bih_l, const float* bhh_l,
                             const float* Wih_r, const float* Whh_r, const float* bih_r, const float* bhh_r,
                             const float* Wenc, const float* benc,
                             u16* wil, u16* whl, u16* wir, u16* whr, u16* we,
                             float* bl, float* br, float* be) {
    const int b = blockIdx.x, t = threadIdx.x;
    if (b < 1024) {
        int o = b*256 + t;                       // [0, 262144)
        int j = o & 7, lane = (o>>3)&63, blk = o>>9;
        int kc = blk&7, g = (blk>>3)&3, u = (blk>>5)&3, wv = blk>>7;
        int lrow = lane&15, quad = lane>>4;
        int s = (g*256 + wv*64 + u*16 + lrow)*256 + kc*32 + quad*8 + j;
        wil[o]=(u16)f2bf(Wih_l[s]); whl[o]=(u16)f2bf(Whh_l[s]);
        wir[o]=(u16)f2bf(Wih_r[s]); whr[o]=(u16)f2bf(Whh_r[s]);
    } else if (b < 1536) {
        int o = (b-1024)*256 + t;                // [0, 131072)
        int j = o & 7, lane = (o>>3)&63, blk = o>>9;
        int kc = blk&7, half = (blk>>3)&1, u2 = (blk>>4)&3, wv = blk>>6;
        int lrow = lane&15, quad = lane>>4;
        int s = (wv*64 + u2*16 + lrow)*512 + half*256 + kc*32 + quad*8 + j;
        we[o] = (u16)f2bf(Wenc[s]);
    } else {
        for (int jj=0;jj<4;++jj){
            int p = jj*256 + t;                  // p = wv*256+g*64+u*16+lrow
            int s = ((p>>6)&3)*256 + ((p>>8)<<6) + (p&63);
            bl[p]=bih_l[s]+bhh_l[s]; br[p]=bih_r[s]+bhh_r[s];
        }
        be[t] = benc[t];
    }
}

// One tree level. 512 threads = 8 waves: waves 0-3 LEFT LSTM, waves 4-7 RIGHT LSTM
// (independent until the encoder). x-tiles are read as MFMA A-fragments DIRECTLY
// from global (shadow rows already match fragment layout; 64B-granule, L1/L2-hit
// on the 4x u-reuse) -> no x_lds, LDS = 2 x 16.9KB = 33.8KB -> up to 4 WGs/CU.
// Leaf (fp32 input, needs conversion) stages x once into h_lds[0] (dead until
// el/er scatter). h deferred-scattered to h_lds[side]; el/er stay in LDS.
template<int NH, int LEAF>
__launch_bounds__(512, 4)
__global__ void level_kernel(const float* __restrict__ node_init, u16* __restrict__ shadow,
    const u16* __restrict__ wil, const u16* __restrict__ whl,
    const u16* __restrict__ wir, const u16* __restrict__ whr,
    const u16* __restrict__ we, const float* __restrict__ bl,
    const float* __restrict__ br, const float* __restrict__ be,
    float* __restrict__ dout,
    int off, int coff, int n, int T, int is_root)
{
    __shared__ __align__(16) u16 h_lds[2][NH*16][264];

    const int tid = threadIdx.x;
    const int side = tid>>8;                  // wave-uniform: 0 = left, 1 = right
    const int wv = (tid>>6)&3, lane = tid&63, lrow = lane&15, quad = lane>>4;
    const int lane8 = lane*8;
    const int nb = blockIdx.x * (NH*16);

    const u16* Wih = side ? wir : wil;
    const u16* Whh = side ? whr : whl;
    const float* bias = side ? br : bl;

    u32 c_pack[4*NH*2];   // bf16x2 c-state
    u32 h_pack[4*NH*2];   // bf16x2 pending h

    for (int t=0; t<T; ++t) {
        // ---- flush prev h_pack -> h_lds[side] ----
        if (t>0) {
#pragma unroll
            for (int u=0; u<4; ++u)
#pragma unroll
            for (int hf=0; hf<NH; ++hf)
#pragma unroll
            for (int rp=0; rp<2; ++rp) {
                u32 p = h_pack[(u*NH+hf)*2+rp];
                int node = hf*16 + quad*4 + rp*2;
                int col = wv*64 + u*16 + lrow;
                h_lds[side][node][col]   = (u16)p;
                h_lds[side][node+1][col] = (u16)(p>>16);
            }
        }
        // ---- leaf: stage converted x tile into h_lds[0] (side-0 threads; T==1) ----
        if constexpr (LEAF) {
            if (side==0) {
                const int stid = tid & 255;
                constexpr int TPR = 256/(NH*16);
                constexpr int GPT = (NH*16)/8;
                const int row = stid / TPR;
                const int sub = stid % TPR;
                int gn = nb + row; if (gn>=n) gn = n-1;
                const float* s = node_init + (size_t)(off+gn)*256 + sub*(GPT*8);
                u16* dd = &h_lds[0][row][sub*(GPT*8)];
#pragma unroll
                for (int q=0;q<GPT;++q) {
                    float4 f0 = ((const float4*)s)[q*2];
                    float4 f1 = ((const float4*)s)[q*2+1];
                    uint4 pk;
                    pk.x = f2bf(f0.x)|(f2bf(f0.y)<<16);
                    pk.y = f2bf(f0.z)|(f2bf(f0.w)<<16);
                    pk.z = f2bf(f1.x)|(f2bf(f1.y)<<16);
                    pk.w = f2bf(f1.z)|(f2bf(f1.w)<<16);
                    ((uint4*)dd)[q] = pk;
                }
            }
        }
        __syncthreads();

        // ---- non-leaf: per-lane x fragment base pointers (direct global A-frags) ----
        const u16* xb[NH];
        if constexpr (!LEAF) {
            const bool own = (side==0) ? (t==T-1) : (t==0);
            const int cidx = (side==0) ? (3-t) : (3+t);
#pragma unroll
            for (int hf=0; hf<NH; ++hf) {
                int gn = nb + hf*16 + lrow; if (gn>=n) gn = n-1;
                size_t grow = own ? (size_t)(off+gn) : ((size_t)coff + (size_t)gn*8 + cidx);
                xb[hf] = shadow + grow*256 + quad*8;
            }
        }

        // ---- GEMM (x@Wih^T [+ h@Whh^T]) + in-register cell update ----
#pragma unroll
        for (int u=0; u<4; ++u) {
            const u16* Wu = Wih + (size_t)(wv*4+u)*16384;
            const u16* Hu = Whh + (size_t)(wv*4+u)*16384;
            f32x4 acc[4][NH];
#pragma unroll
            for (int g=0; g<4; ++g) {
                float bv = bias[wv*256 + g*64 + u*16 + lrow];
#pragma unroll
                for (int hf=0; hf<NH; ++hf) acc[g][hf] = (f32x4){bv,bv,bv,bv};
            }
#pragma unroll 2
            for (int kc=0; kc<8; ++kc) {
                s16x8 a[NH];
#pragma unroll
                for (int hf=0; hf<NH; ++hf) {
                    if constexpr (LEAF)
                        a[hf] = *(const s16x8*)&h_lds[0][hf*16+lrow][kc*32 + quad*8];
                    else
                        a[hf] = *(const s16x8*)(xb[hf] + kc*32);
                }
#pragma unroll
                for (int g=0; g<4; ++g) {
                    s16x8 bw = *(const s16x8*)(Wu + ((g*8+kc)<<9) + lane8);
#pragma unroll
                    for (int hf=0; hf<NH; ++hf) acc[g][hf] = MFMA(a[hf], bw, acc[g][hf]);
                }
            }
            if (t>0) {
#pragma unroll 2
                for (int kc=0; kc<8; ++kc) {
                    s16x8 a[NH];
#pragma unroll
                    for (int hf=0; hf<NH; ++hf)
                        a[hf] = *(const s16x8*)&h_lds[side][hf*16+lrow][kc*32 + quad*8];
#pragma unroll
                    for (int g=0; g<4; ++g) {
                        s16x8 bw = *(const s16x8*)(Hu + ((g*8+kc)<<9) + lane8);
#pragma unroll
                        for (int hf=0; hf<NH; ++hf) acc[g][hf] = MFMA(a[hf], bw, acc[g][hf]);
                    }
                }
            }
#pragma unroll
            for (int hf=0; hf<NH; ++hf) {
#pragma unroll
                for (int rp=0; rp<2; ++rp) {
                    int r0 = rp*2, r1 = rp*2+1;
                    float iv0 = sigm(acc[0][hf][r0]), iv1 = sigm(acc[0][hf][r1]);
                    float fv0 = sigm(acc[1][hf][r0]), fv1 = sigm(acc[1][hf][r1]);
                    float gv0 = tanh_(acc[2][hf][r0]), gv1 = tanh_(acc[2][hf][r1]);
                    float ov0 = sigm(acc[3][hf][r0]), ov1 = sigm(acc[3][hf][r1]);
                    int pi = (u*NH+hf)*2 + rp;
                    float c0 = iv0*gv0, c1 = iv1*gv1;
                    if (t>0) { u32 cp = c_pack[pi]; c0 += fv0*bflo(cp); c1 += fv1*bfhi(cp); }
                    c_pack[pi] = f2bf(c0) | (f2bf(c1)<<16);
                    float h0 = ov0*tanh_(c0), h1 = ov1*tanh_(c1);
                    h_pack[pi] = f2bf(h0) | (f2bf(h1)<<16);
                }
            }
            __builtin_amdgcn_sched_barrier(0);   // serialize u-subtiles: cap live regs
        }
        __syncthreads();
    } // t

    // ---- scatter final h: el -> h_lds[0], er -> h_lds[1] ----
#pragma unroll
    for (int u=0; u<4; ++u)
#pragma unroll
    for (int hf=0; hf<NH; ++hf)
#pragma unroll
    for (int rp=0; rp<2; ++rp) {
        u32 p = h_pack[(u*NH+hf)*2+rp];
        int node = hf*16 + quad*4 + rp*2;
        int col = wv*64 + u*16 + lrow;
        h_lds[side][node][col]   = (u16)p;
        h_lds[side][node+1][col] = (u16)(p>>16);
    }
    __syncthreads();

    // ---- encoder: 8 waves x 32 features each; el/er both from LDS ----
    const int w8 = tid>>6;
    f32x4 acc2[2][NH];
#pragma unroll
    for (int u2=0; u2<2; ++u2) {
        const u16* Eu = we + (size_t)((w8>>1)*4 + (w8&1)*2 + u2)*8192;
        const int ce = w8*32 + u2*16 + lrow;
        float bv = be[ce];
#pragma unroll
        for (int hf=0; hf<NH; ++hf) acc2[u2][hf] = (f32x4){bv,bv,bv,bv};
#pragma unroll 2
        for (int kc=0; kc<8; ++kc) {
            s16x8 a0[NH], a1[NH];
#pragma unroll
            for (int hf=0; hf<NH; ++hf) {
                a0[hf] = *(const s16x8*)&h_lds[0][hf*16+lrow][kc*32+quad*8];   // el
                a1[hf] = *(const s16x8*)&h_lds[1][hf*16+lrow][kc*32+quad*8];   // er
            }
            s16x8 b0 = *(const s16x8*)(Eu + (kc<<9) + lane8);
            s16x8 b1 = *(const s16x8*)(Eu + ((8+kc)<<9) + lane8);
#pragma unroll
            for (int hf=0; hf<NH; ++hf) {
                acc2[u2][hf] = MFMA(a0[hf], b0, acc2[u2][hf]);
                acc2[u2][hf] = MFMA(a1[hf], b1, acc2[u2][hf]);
            }
        }
        __builtin_amdgcn_sched_barrier(0);
    }
    __syncthreads();   // all encoder reads of h_lds[0] done before overwrite
    // tanh + scatter enc (bf16) into h_lds[0]; root also writes fp32 dout
#pragma unroll
    for (int u2=0; u2<2; ++u2) {
        const int ce = w8*32 + u2*16 + lrow;
#pragma unroll
        for (int hf=0; hf<NH; ++hf) {
#pragma unroll
            for (int r=0; r<4; ++r) {
                float v = tanh_(acc2[u2][hf][r]);
                int node = hf*16+quad*4+r;
                h_lds[0][node][ce] = (u16)f2bf(v);
                if (is_root && node==0) dout[ce] = v;
            }
        }
    }
    __syncthreads();
    // ---- coalesced copyout h_lds[0] -> shadow[off..] (512 threads) ----
    {
        constexpr int TPR2 = 512/(NH*16);    // NH=2 -> 16, NH=1 -> 32
        constexpr int GPT2 = (NH*16)/16;     // NH=2 -> 2,  NH=1 -> 1
        const int row = tid / TPR2;
        const int sub = tid % TPR2;
        int gn = nb+row; if (gn>=n) gn=n-1;
        u16* d = shadow + (size_t)(off+gn)*256 + sub*(GPT2*8);
        const u16* s = &h_lds[0][row][sub*(GPT2*8)];
#pragma unroll
        for (int q=0;q<GPT2;++q) ((uint4*)d)[q] = ((const uint4*)s)[q];
    }
}

extern "C" void kernel_launch(void* const* d_in, const int* in_sizes, int n_in,
                              void* d_out, int out_size, void* d_ws, size_t ws_size,
                              hipStream_t stream) {
    (void)in_sizes; (void)n_in; (void)out_size; (void)ws_size;
    const float* node_init = (const float*)d_in[0];
    const float* Wih_l = (const float*)d_in[1];
    const float* Whh_l = (const float*)d_in[2];
    const float* bih_l = (const float*)d_in[3];
    const float* bhh_l = (const float*)d_in[4];
    const float* Wih_r = (const float*)d_in[5];
    const float* Whh_r = (const float*)d_in[6];
    const float* bih_r = (const float*)d_in[7];
    const float* bhh_r = (const float*)d_in[8];
    const float* Wenc  = (const float*)d_in[9];
    const float* benc  = (const float*)d_in[10];

    u16* shadow = (u16*)d_ws;                      // 299593*256 bf16 = 153.4 MB
    u16* wil = shadow + (size_t)299593*256;
    u16* whl = wil + 262144;
    u16* wir = whl + 262144;
    u16* whr = wir + 262144;
    u16* we  = whr + 262144;                       // 131072
    float* bl = (float*)(we + 131072);
    float* br = bl + 1024;
    float* be = br + 1024;

    // convert only non-leaf own rows [0, 37449): 37449*256/8 = 1198368 chunks
    conv_nodes<<<dim3(4682), dim3(256), 0, stream>>>(node_init, shadow, 1198368L);
    prep_weights<<<dim3(1537), dim3(256), 0, stream>>>(
        Wih_l, Whh_l, bih_l, bhh_l, Wih_r, Whh_r, bih_r, bhh_r, Wenc, benc,
        wil, whl, wir, whr, we, bl, br, be);

    static const int OFF[8] = {0, 1, 9, 73, 585, 4681, 37449, 299593};
    static const int SZ[7]  = {1, 8, 64, 512, 4096, 32768, 262144};

    for (int d = 6; d >= 0; --d) {
        const int n = SZ[d];
        const int T = (d == 6) ? 1 : 5;
        const int root = (d == 0) ? 1 : 0;
        const int coff = (d < 6) ? OFF[d+1] : 0;
        if (d == 6) {
            level_kernel<2,1><<<dim3((n+31)/32), dim3(512), 0, stream>>>(
                node_init, shadow, wil, whl, wir, whr, we, bl, br, be,
                (float*)d_out, OFF[d], coff, n, T, root);
        } else if (d == 5) {
            level_kernel<2,0><<<dim3((n+31)/32), dim3(512), 0, stream>>>(
                node_init, shadow, wil, whl, wir, whr, we, bl, br, be,
                (float*)d_out, OFF[d], coff, n, T, root);
        } else {
            level_kernel<1,0><<<dim3((n+15)/16), dim3(512), 0, stream>>>(
                node_init, shadow, wil, whl, wir, whr, we, bl, br, be,
                (float*)d_out, OFF[d], coff, n, T, root);
        }
    }
}

// Round 5
// 2217.744 us; speedup vs baseline: 1.0706x; 1.0706x over previous
//
#include <hip/hip_runtime.h>
#include <cstdint>
#include <cstddef>

typedef unsigned int u32;
typedef unsigned short u16;
typedef __attribute__((ext_vector_type(8))) short s16x8;
typedef __attribute__((ext_vector_type(4))) float f32x4;

#define MFMA(a,b,c) __builtin_amdgcn_mfma_f32_16x16x32_bf16((a),(b),(c),0,0,0)

__device__ __forceinline__ u32 f2bf(float f){ union{float f;u32 u;}v; v.f=f; return (v.u + 0x7FFFu + ((v.u>>16)&1u))>>16; }
__device__ __forceinline__ float bflo(u32 p){ union{u32 u;float f;}v; v.u=p<<16; return v.f; }
__device__ __forceinline__ float bfhi(u32 p){ union{u32 u;float f;}v; v.u=p&0xFFFF0000u; return v.f; }
__device__ __forceinline__ float sigm(float x){ return __builtin_amdgcn_rcpf(1.0f + __builtin_amdgcn_exp2f(-1.4426950408889634f*x)); }
__device__ __forceinline__ float tanh_(float x){ return 1.0f - 2.0f*__builtin_amdgcn_rcpf(1.0f + __builtin_amdgcn_exp2f(2.8853900817779268f*x)); }

// node_init (fp32) -> shadow (bf16) for non-leaf own rows [0, 37449). total8 = elems/8.
__global__ void conv_nodes(const float* __restrict__ src, u16* __restrict__ dst, long total8) {
    long i = (long)blockIdx.x*256 + threadIdx.x;
    if (i < total8) {
        const float* s = src + i*8;
        float4 f0 = *(const float4*)s;
        float4 f1 = *(const float4*)(s+4);
        uint4 pk;
        pk.x = f2bf(f0.x) | (f2bf(f0.y)<<16);
        pk.y = f2bf(f0.z) | (f2bf(f0.w)<<16);
        pk.z = f2bf(f1.x) | (f2bf(f1.y)<<16);
        pk.w = f2bf(f1.z) | (f2bf(f1.w)<<16);
        *(uint4*)(dst + i*8) = pk;
    }
}

// Packed weight layout (gather-free B-fragments):
// LSTM mats: block b = ((wv*4+u)*4+g)*8+kc, flat = b*512 + lane*8 + j
//   source row (torch order) = g*256 + wv*64 + u*16 + lrow, col = kc*32 + quad*8 + j
// Wenc: block = ((wv*4+u2)*2+half)*8+kc, flat = blk*512 + lane*8 + j
//   source row ce = wv*64+u2*16+lrow, col = half*256 + kc*32 + quad*8 + j
__global__ void prep_weights(const float* Wih_l, const float* Whh_l, const float* bih_l, const float* bhh_l,
                             const float* Wih_r, const float* Whh_r, const float* bih_r, const float* bhh_r,
                             const float* Wenc, const float* benc,
                             u16* wil, u16* whl, u16* wir, u16* whr, u16* we,
                             float* bl, float* br, float* be) {
    const int b = blockIdx.x, t = threadIdx.x;
    if (b < 1024) {
        int o = b*256 + t;                       // [0, 262144)
        int j = o & 7, lane = (o>>3)&63, blk = o>>9;
        int kc = blk&7, g = (blk>>3)&3, u = (blk>>5)&3, wv = blk>>7;
        int lrow = lane&15, quad = lane>>4;
        int s = (g*256 + wv*64 + u*16 + lrow)*256 + kc*32 + quad*8 + j;
        wil[o]=(u16)f2bf(Wih_l[s]); whl[o]=(u16)f2bf(Whh_l[s]);
        wir[o]=(u16)f2bf(Wih_r[s]); whr[o]=(u16)f2bf(Whh_r[s]);
    } else if (b < 1536) {
        int o = (b-1024)*256 + t;                // [0, 131072)
        int j = o & 7, lane = (o>>3)&63, blk = o>>9;
        int kc = blk&7, half = (blk>>3)&1, u2 = (blk>>4)&3, wv = blk>>6;
        int lrow = lane&15, quad = lane>>4;
        int s = (wv*64 + u2*16 + lrow)*512 + half*256 + kc*32 + quad*8 + j;
        we[o] = (u16)f2bf(Wenc[s]);
    } else {
        for (int jj=0;jj<4;++jj){
            int p = jj*256 + t;                  // p = wv*256+g*64+u*16+lrow
            int s = ((p>>6)&3)*256 + ((p>>8)<<6) + (p&63);
            bl[p]=bih_l[s]+bhh_l[s]; br[p]=bih_r[s]+bhh_r[s];
        }
        be[t] = benc[t];
    }
}

// One tree level. 512 threads = 8 waves: waves 0-3 LEFT LSTM, waves 4-7 RIGHT LSTM
// (independent until the encoder). Wave wv computes all 4 gates for features
// [wv*64, wv*64+64); cell update in registers (c packed bf16x2); h deferred-
// scattered to h_lds[side]. el/er stay in LDS for the encoder.
// NO sched_barrier in the u-loop: occupancy is register-bucketed at 4 waves/SIMD
// for total regs in (85,128]; we use ~96, so letting the compiler pipeline
// u+1's weight loads into u's MFMA/activation window is free (launch_bounds
// caps at 128 so occupancy cannot drop below 2 WGs/CU).
template<int NH>
__launch_bounds__(512, 4)
__global__ void level_kernel(const float* __restrict__ node_init, u16* __restrict__ shadow,
    const u16* __restrict__ wil, const u16* __restrict__ whl,
    const u16* __restrict__ wir, const u16* __restrict__ whr,
    const u16* __restrict__ we, const float* __restrict__ bl,
    const float* __restrict__ br, const float* __restrict__ be,
    float* __restrict__ dout,
    int off, int coff, int n, int T, int is_leaf, int is_root)
{
    __shared__ __align__(16) u16 x_lds[2][NH*16][264];
    __shared__ __align__(16) u16 h_lds[2][NH*16][264];

    const int tid = threadIdx.x;
    const int side = tid>>8;                  // wave-uniform: 0 = left, 1 = right
    const int wv = (tid>>6)&3, lane = tid&63, lrow = lane&15, quad = lane>>4;
    const int lane8 = lane*8;
    const int nb = blockIdx.x * (NH*16);

    const u16* Wih = side ? wir : wil;
    const u16* Whh = side ? whr : whl;
    const float* bias = side ? br : bl;
    const int xs = is_leaf ? 0 : side;        // leaf: both sides read x_lds[0]

    u32 c_pack[4*NH*2];   // bf16x2 c-state
    u32 h_pack[4*NH*2];   // bf16x2 pending h

    for (int t=0; t<T; ++t) {
        // ---- flush prev h_pack -> h_lds[side] ----
        if (t>0) {
#pragma unroll
            for (int u=0; u<4; ++u)
#pragma unroll
            for (int hf=0; hf<NH; ++hf)
#pragma unroll
            for (int rp=0; rp<2; ++rp) {
                u32 p = h_pack[(u*NH+hf)*2+rp];
                int node = hf*16 + quad*4 + rp*2;
                int col = wv*64 + u*16 + lrow;
                h_lds[side][node][col]   = (u16)p;
                h_lds[side][node+1][col] = (u16)(p>>16);
            }
        }
        // ---- stage x tile (256 threads per side; leaf: side 0 only) ----
        if (!is_leaf || side==0) {
            const int stid = tid & 255;
            constexpr int TPR = 256/(NH*16);     // threads per row: NH=2 -> 8, NH=1 -> 16
            constexpr int GPT = (NH*16)/8;       // uint4 per thread:  NH=2 -> 4, NH=1 -> 2
            const int row = stid / TPR;
            const int sub = stid % TPR;
            int gn = nb + row; if (gn>=n) gn = n-1;
            if (is_leaf) {
                const float* s = node_init + (size_t)(off+gn)*256 + sub*(GPT*8);
                u16* dd = &x_lds[0][row][sub*(GPT*8)];
#pragma unroll
                for (int q=0;q<GPT;++q) {
                    float4 f0 = ((const float4*)s)[q*2];
                    float4 f1 = ((const float4*)s)[q*2+1];
                    uint4 pk;
                    pk.x = f2bf(f0.x)|(f2bf(f0.y)<<16);
                    pk.y = f2bf(f0.z)|(f2bf(f0.w)<<16);
                    pk.z = f2bf(f1.x)|(f2bf(f1.y)<<16);
                    pk.w = f2bf(f1.z)|(f2bf(f1.w)<<16);
                    ((uint4*)dd)[q] = pk;
                }
            } else {
                const bool own = (side==0) ? (t==T-1) : (t==0);
                const int cidx = (side==0) ? (3-t) : (3+t);
                size_t grow = own ? (size_t)(off+gn) : ((size_t)coff + (size_t)gn*8 + cidx);
                const u16* s = shadow + grow*256 + sub*(GPT*8);
                u16* dd = &x_lds[side][row][sub*(GPT*8)];
#pragma unroll
                for (int q=0;q<GPT;++q) ((uint4*)dd)[q] = ((const uint4*)s)[q];
            }
        }
        __syncthreads();

        // ---- GEMM (x@Wih^T [+ h@Whh^T]) + in-register cell update ----
#pragma unroll
        for (int u=0; u<4; ++u) {
            const u16* Wu = Wih + (size_t)(wv*4+u)*16384;
            const u16* Hu = Whh + (size_t)(wv*4+u)*16384;
            f32x4 acc[4][NH];
#pragma unroll
            for (int g=0; g<4; ++g) {
                float bv = bias[wv*256 + g*64 + u*16 + lrow];
#pragma unroll
                for (int hf=0; hf<NH; ++hf) acc[g][hf] = (f32x4){bv,bv,bv,bv};
            }
#pragma unroll 2
            for (int kc=0; kc<8; ++kc) {
                s16x8 a[NH];
#pragma unroll
                for (int hf=0; hf<NH; ++hf)
                    a[hf] = *(const s16x8*)&x_lds[xs][hf*16+lrow][kc*32 + quad*8];
#pragma unroll
                for (int g=0; g<4; ++g) {
                    s16x8 bw = *(const s16x8*)(Wu + ((g*8+kc)<<9) + lane8);
#pragma unroll
                    for (int hf=0; hf<NH; ++hf) acc[g][hf] = MFMA(a[hf], bw, acc[g][hf]);
                }
            }
            if (t>0) {
#pragma unroll 2
                for (int kc=0; kc<8; ++kc) {
                    s16x8 a[NH];
#pragma unroll
                    for (int hf=0; hf<NH; ++hf)
                        a[hf] = *(const s16x8*)&h_lds[side][hf*16+lrow][kc*32 + quad*8];
#pragma unroll
                    for (int g=0; g<4; ++g) {
                        s16x8 bw = *(const s16x8*)(Hu + ((g*8+kc)<<9) + lane8);
#pragma unroll
                        for (int hf=0; hf<NH; ++hf) acc[g][hf] = MFMA(a[hf], bw, acc[g][hf]);
                    }
                }
            }
#pragma unroll
            for (int hf=0; hf<NH; ++hf) {
#pragma unroll
                for (int rp=0; rp<2; ++rp) {
                    int r0 = rp*2, r1 = rp*2+1;
                    float iv0 = sigm(acc[0][hf][r0]), iv1 = sigm(acc[0][hf][r1]);
                    float fv0 = sigm(acc[1][hf][r0]), fv1 = sigm(acc[1][hf][r1]);
                    float gv0 = tanh_(acc[2][hf][r0]), gv1 = tanh_(acc[2][hf][r1]);
                    float ov0 = sigm(acc[3][hf][r0]), ov1 = sigm(acc[3][hf][r1]);
                    int pi = (u*NH+hf)*2 + rp;
                    float c0 = iv0*gv0, c1 = iv1*gv1;
                    if (t>0) { u32 cp = c_pack[pi]; c0 += fv0*bflo(cp); c1 += fv1*bfhi(cp); }
                    c_pack[pi] = f2bf(c0) | (f2bf(c1)<<16);
                    float h0 = ov0*tanh_(c0), h1 = ov1*tanh_(c1);
                    h_pack[pi] = f2bf(h0) | (f2bf(h1)<<16);
                }
            }
        }
        __syncthreads();
    } // t

    // ---- scatter final h: el -> h_lds[0], er -> h_lds[1] ----
#pragma unroll
    for (int u=0; u<4; ++u)
#pragma unroll
    for (int hf=0; hf<NH; ++hf)
#pragma unroll
    for (int rp=0; rp<2; ++rp) {
        u32 p = h_pack[(u*NH+hf)*2+rp];
        int node = hf*16 + quad*4 + rp*2;
        int col = wv*64 + u*16 + lrow;
        h_lds[side][node][col]   = (u16)p;
        h_lds[side][node+1][col] = (u16)(p>>16);
    }
    __syncthreads();

    // ---- encoder: 8 waves x 32 features each; el/er both from LDS ----
    const int w8 = tid>>6;
    f32x4 acc2[2][NH];
#pragma unroll
    for (int u2=0; u2<2; ++u2) {
        const u16* Eu = we + (size_t)((w8>>1)*4 + (w8&1)*2 + u2)*8192;
        const int ce = w8*32 + u2*16 + lrow;
        float bv = be[ce];
#pragma unroll
        for (int hf=0; hf<NH; ++hf) acc2[u2][hf] = (f32x4){bv,bv,bv,bv};
#pragma unroll 2
        for (int kc=0; kc<8; ++kc) {
            s16x8 a0[NH], a1[NH];
#pragma unroll
            for (int hf=0; hf<NH; ++hf) {
                a0[hf] = *(const s16x8*)&h_lds[0][hf*16+lrow][kc*32+quad*8];   // el
                a1[hf] = *(const s16x8*)&h_lds[1][hf*16+lrow][kc*32+quad*8];   // er
            }
            s16x8 b0 = *(const s16x8*)(Eu + (kc<<9) + lane8);
            s16x8 b1 = *(const s16x8*)(Eu + ((8+kc)<<9) + lane8);
#pragma unroll
            for (int hf=0; hf<NH; ++hf) {
                acc2[u2][hf] = MFMA(a0[hf], b0, acc2[u2][hf]);
                acc2[u2][hf] = MFMA(a1[hf], b1, acc2[u2][hf]);
            }
        }
    }
    // tanh + scatter enc (bf16) into x_lds[0]; root also writes fp32 dout
#pragma unroll
    for (int u2=0; u2<2; ++u2) {
        const int ce = w8*32 + u2*16 + lrow;
#pragma unroll
        for (int hf=0; hf<NH; ++hf) {
#pragma unroll
            for (int r=0; r<4; ++r) {
                float v = tanh_(acc2[u2][hf][r]);
                int node = hf*16+quad*4+r;
                x_lds[0][node][ce] = (u16)f2bf(v);
                if (is_root && node==0) dout[ce] = v;
            }
        }
    }
    __syncthreads();
    // ---- coalesced copyout x_lds[0] -> shadow[off..] (512 threads) ----
    {
        constexpr int TPR2 = 512/(NH*16);    // NH=2 -> 16, NH=1 -> 32
        constexpr int GPT2 = (NH*16)/16;     // NH=2 -> 2,  NH=1 -> 1
        const int row = tid / TPR2;
        const int sub = tid % TPR2;
        int gn = nb+row; if (gn>=n) gn=n-1;
        u16* d = shadow + (size_t)(off+gn)*256 + sub*(GPT2*8);
        const u16* s = &x_lds[0][row][sub*(GPT2*8)];
#pragma unroll
        for (int q=0;q<GPT2;++q) ((uint4*)d)[q] = ((const uint4*)s)[q];
    }
}

extern "C" void kernel_launch(void* const* d_in, const int* in_sizes, int n_in,
                              void* d_out, int out_size, void* d_ws, size_t ws_size,
                              hipStream_t stream) {
    (void)in_sizes; (void)n_in; (void)out_size; (void)ws_size;
    const float* node_init = (const float*)d_in[0];
    const float* Wih_l = (const float*)d_in[1];
    const float* Whh_l = (const float*)d_in[2];
    const float* bih_l = (const float*)d_in[3];
    const float* bhh_l = (const float*)d_in[4];
    const float* Wih_r = (const float*)d_in[5];
    const float* Whh_r = (const float*)d_in[6];
    const float* bih_r = (const float*)d_in[7];
    const float* bhh_r = (const float*)d_in[8];
    const float* Wenc  = (const float*)d_in[9];
    const float* benc  = (const float*)d_in[10];

    u16* shadow = (u16*)d_ws;                      // 299593*256 bf16 = 153.4 MB
    u16* wil = shadow + (size_t)299593*256;
    u16* whl = wil + 262144;
    u16* wir = whl + 262144;
    u16* whr = wir + 262144;
    u16* we  = whr + 262144;                       // 131072
    float* bl = (float*)(we + 131072);
    float* br = bl + 1024;
    float* be = br + 1024;

    // convert only non-leaf own rows [0, 37449): 37449*256/8 = 1198368 chunks
    conv_nodes<<<dim3(4682), dim3(256), 0, stream>>>(node_init, shadow, 1198368L);
    prep_weights<<<dim3(1537), dim3(256), 0, stream>>>(
        Wih_l, Whh_l, bih_l, bhh_l, Wih_r, Whh_r, bih_r, bhh_r, Wenc, benc,
        wil, whl, wir, whr, we, bl, br, be);

    static const int OFF[8] = {0, 1, 9, 73, 585, 4681, 37449, 299593};
    static const int SZ[7]  = {1, 8, 64, 512, 4096, 32768, 262144};

    for (int d = 6; d >= 0; --d) {
        const int n = SZ[d];
        const int T = (d == 6) ? 1 : 5;
        const int leaf = (d == 6) ? 1 : 0;
        const int root = (d == 0) ? 1 : 0;
        const int coff = (d < 6) ? OFF[d+1] : 0;
        if (d >= 5) {
            level_kernel<2><<<dim3((n+31)/32), dim3(512), 0, stream>>>(
                node_init, shadow, wil, whl, wir, whr, we, bl, br, be,
                (float*)d_out, OFF[d], coff, n, T, leaf, root);
        } else {
            level_kernel<1><<<dim3((n+15)/16), dim3(512), 0, stream>>>(
                node_init, shadow, wil, whl, wir, whr, we, bl, br, be,
                (float*)d_out, OFF[d], coff, n, T, leaf, root);
        }
    }
}